// Round 12
// baseline (1500.738 us; speedup 1.0000x reference)
//
#include <hip/hip_runtime.h>

#define NE 32
#define NG 8
#define NK 4
#define ND 2048
#define NH 1024
#define NHS 4096
#define CAPE 1024
#define NT 4096

typedef float f32x4 __attribute__((ext_vector_type(4)));
typedef short s16x8 __attribute__((ext_vector_type(8)));

__device__ __forceinline__ short f2bf(float f) {
    return __builtin_bit_cast(short, (__bf16)f);
}
__device__ __forceinline__ float bf2f(short h) {
    return __builtin_bit_cast(float, ((unsigned)(unsigned short)h) << 16);
}

__device__ __forceinline__ void gload_lds16(const void* g, void* l) {
    __builtin_amdgcn_global_load_lds(
        (const __attribute__((address_space(1))) void*)g,
        (__attribute__((address_space(3))) void*)l, 16, 0, 0);
}

// ---------------------------------------------------------------------------
// Kernel 1: gating. One wave per token. fp32 logits, sigmoid, grouped top-k.
// ---------------------------------------------------------------------------
__global__ __launch_bounds__(256) void gate_kernel(
    const float* __restrict__ X, const float* __restrict__ Gw,
    const float* __restrict__ bias,
    int* __restrict__ topk_idx, float* __restrict__ topk_w)
{
    const int lane = threadIdx.x & 63;
    const int t = blockIdx.x * 4 + (threadIdx.x >> 6);
    const float* x = X + (size_t)t * ND;

    float xr[32];
#pragma unroll
    for (int i = 0; i < 32; i++) xr[i] = x[lane + i * 64];

    float scores[32];
#pragma unroll
    for (int e = 0; e < 32; e++) {
        const float* w = Gw + (size_t)e * ND;
        float a = 0.f;
#pragma unroll
        for (int i = 0; i < 32; i++) a = fmaf(xr[i], w[lane + i * 64], a);
#pragma unroll
        for (int s = 32; s > 0; s >>= 1) a += __shfl_xor(a, s);
        scores[e] = 1.0f / (1.0f + expf(-a));
    }

    float sc_c[32];
#pragma unroll
    for (int e = 0; e < 32; e++) sc_c[e] = scores[e] + bias[e];

    float gs[8];
#pragma unroll
    for (int g = 0; g < 8; g++) {
        float a = sc_c[4 * g], b = sc_c[4 * g + 1], c = sc_c[4 * g + 2], d = sc_c[4 * g + 3];
        float hi1 = fmaxf(a, b), lo1 = fminf(a, b);
        float hi2 = fmaxf(c, d), lo2 = fminf(c, d);
        float m1 = fmaxf(hi1, hi2);
        float m2 = fmaxf(fminf(hi1, hi2), fmaxf(lo1, lo2));
        gs[g] = m1 + m2;
    }

    unsigned gsel = 0;
#pragma unroll
    for (int it = 0; it < 4; it++) {
        int best = -1; float bv = -1e30f;
#pragma unroll
        for (int g = 0; g < 8; g++) {
            bool avail = !((gsel >> g) & 1);
            if (avail && gs[g] > bv) { bv = gs[g]; best = g; }
        }
        gsel |= 1u << best;
    }

    unsigned esel = 0;
    int idxs[4]; float wts[4];
#pragma unroll
    for (int it = 0; it < 4; it++) {
        int best = -1; float bv = -1e30f, braw = 0.f;
#pragma unroll
        for (int e = 0; e < 32; e++) {
            float mv = ((gsel >> (e >> 2)) & 1) ? sc_c[e] : 0.0f;
            bool avail = !((esel >> e) & 1);
            if (avail && mv > bv) { bv = mv; best = e; braw = scores[e]; }
        }
        esel |= 1u << best;
        idxs[it] = best; wts[it] = braw;
    }

    float s = wts[0] + wts[1] + wts[2] + wts[3] + 1e-20f;
    if (lane == 0) {
#pragma unroll
        for (int k = 0; k < 4; k++) {
            topk_idx[t * 4 + k] = idxs[k];
            topk_w[t * 4 + k] = wts[k] / s * 2.5f;
        }
    }
}

// ---------------------------------------------------------------------------
__global__ void zero_cnt(int* cnt) {
    if (threadIdx.x < NE) cnt[threadIdx.x] = 0;
}

__global__ void dispatch_kernel(const int* __restrict__ topk_idx,
                                int* __restrict__ cnt,
                                int* __restrict__ tok_list,
                                int* __restrict__ pos_list)
{
    int i = blockIdx.x * 256 + threadIdx.x;
    int e = topk_idx[i];
    int t = i >> 2;
    int pos = atomicAdd(&cnt[e], 1);
    pos_list[i] = pos;
    if (pos < CAPE) {
        tok_list[e * CAPE + pos] = t;
    }
}

// ---------------------------------------------------------------------------
// f32 -> bf16 bulk conversion (only used for X; weights consumed as f32)
// ---------------------------------------------------------------------------
__global__ __launch_bounds__(256) void cvt_f2bf(const float* __restrict__ in,
                                                short* __restrict__ out, int n8)
{
    int i = blockIdx.x * 256 + threadIdx.x;
    int stride = gridDim.x * 256;
    for (; i < n8; i += stride) {
        const f32x4* p = (const f32x4*)(in + (size_t)i * 8);
        f32x4 a = p[0], b = p[1];
        s16x8 h;
        h[0] = f2bf(a[0]); h[1] = f2bf(a[1]); h[2] = f2bf(a[2]); h[3] = f2bf(a[3]);
        h[4] = f2bf(b[0]); h[5] = f2bf(b[1]); h[6] = f2bf(b[2]); h[7] = f2bf(b[3]);
        *(s16x8*)(out + (size_t)i * 8) = h;
    }
}

// ---------------------------------------------------------------------------
// Combine: out[t] = shared_down[t] (already in out) + sum_k w_k * Ybuf[e_k,pos_k]
// ---------------------------------------------------------------------------
__global__ __launch_bounds__(256) void combine_kernel(
    const int* __restrict__ topk_idx, const float* __restrict__ topk_w,
    const int* __restrict__ pos_list,
    const short* __restrict__ Ybuf, float* __restrict__ out)
{
    const int t = blockIdx.x;
    const int d0 = threadIdx.x * 8;

    int e[NK], p[NK]; float w[NK];
#pragma unroll
    for (int k = 0; k < NK; k++) {
        e[k] = topk_idx[t * NK + k];
        p[k] = pos_list[t * NK + k];
        w[k] = topk_w[t * NK + k];
    }

    float* orow = out + (size_t)t * ND + d0;
    f32x4 o0 = *(f32x4*)(orow);
    f32x4 o1 = *(f32x4*)(orow + 4);

#pragma unroll
    for (int k = 0; k < NK; k++) {
        if (p[k] < CAPE) {
            s16x8 y = *(const s16x8*)(Ybuf + ((size_t)e[k] * CAPE + p[k]) * ND + d0);
            o0[0] = fmaf(w[k], bf2f(y[0]), o0[0]);
            o0[1] = fmaf(w[k], bf2f(y[1]), o0[1]);
            o0[2] = fmaf(w[k], bf2f(y[2]), o0[2]);
            o0[3] = fmaf(w[k], bf2f(y[3]), o0[3]);
            o1[0] = fmaf(w[k], bf2f(y[4]), o1[0]);
            o1[1] = fmaf(w[k], bf2f(y[5]), o1[1]);
            o1[2] = fmaf(w[k], bf2f(y[6]), o1[2]);
            o1[3] = fmaf(w[k], bf2f(y[7]), o1[3]);
        }
    }
    *(f32x4*)(orow) = o0;
    *(f32x4*)(orow + 4) = o1;
}

// ---------------------------------------------------------------------------
// 4-wave GEMM (R10 structure + 4-deep B pipeline): 128x128, BK=64,
// LDS: As[2] + Bs[2] x 16KB = 64 KB -> 2 blocks/CU.
// A (bf16, cache-resident stream): gload_lds, pre-swizzled source.
// B (f32 HBM stream): 4-deep reg pipeline (br0..br3) -> cvt -> swizzled
// ds_write. Ledger: iter T issues STAGE_A(T+2)[4] + BLOAD(T+4)[8]; steady
// queue = [B(T+2)8, A(T+1)4, B(T+3)8, A(T+2)4, B(T+4)8] = 32; vmcnt(20)
// retires exactly {B(T+2), A(T+1)}. BWRITE consumes B(T+1) (retired at T-1)
// -> B gets 3 iters (~1000 cyc) of HBM-latency cover; A ~1.5 iters (L2-hit).
// MODE 0: routed up   (A = Xbf gathered,  B = up_w[e],  out = relu2 -> Hbuf)
// MODE 1: routed down (A = Hbuf[e],       B = dn_w[e],  out = Ybuf bf16)
// MODE 2: shared up   (A = Xbf,           B = sup,      out = relu2 -> Sbuf)
// MODE 3: shared down (A = Sbuf,          B = sdn,      out = f32 write)
// ---------------------------------------------------------------------------
template <int MODE>
__global__ __launch_bounds__(256, 2) void moe_gemm4(
    const short* __restrict__ Abase, const float* __restrict__ Bbase,
    const int* __restrict__ cnt, const int* __restrict__ tok_list,
    short* __restrict__ Hout, float* __restrict__ out)
{
    constexpr int K = (MODE == 0) ? ND : (MODE == 1) ? NH : (MODE == 2) ? ND : NHS;
    constexpr int NTILES = K / 64;   // 32, 16, 32, 64 — all divisible by 4

    const int e = blockIdx.z;
    const int m0 = blockIdx.y * 128, n0 = blockIdx.x * 128;

    int mcnt = 0;
    if constexpr (MODE == 0 || MODE == 1) {
        mcnt = min(cnt[e], CAPE);
        if (m0 >= mcnt) return;
    }

    __shared__ short As[2][128 * 64];
    __shared__ short Bs[2][128 * 64];

    const int tid = threadIdx.x;
    const int lane = tid & 63;
    const int wave = tid >> 6;
    const int wr = wave >> 1, wc = wave & 1;     // 2x2 wave grid, 64x64 each

    const short* Ab = Abase;
    const float* Bb = Bbase;
    if constexpr (MODE == 0) Bb += (size_t)e * NH * ND;
    if constexpr (MODE == 1) { Ab += (size_t)e * CAPE * NH; Bb += (size_t)e * ND * NH; }

    // ---- A staging (gload_lds): op = 32 rows x 64 elems ----
    const int srow = tid >> 3;                  // 0..31 row within op
    const int pA = tid & 7;                     // phys 16B slot 0..7
    const int gcolA = (pA ^ (srow & 7)) * 8;    // inverse-swizzled global col
    const short* asrc[4];
    int dstA[4];
#pragma unroll
    for (int o = 0; o < 4; o++) {
        int r = o * 32 + srow;
        if constexpr (MODE == 0) {
            int gr = min(m0 + r, mcnt - 1);
            int tok = tok_list[e * CAPE + gr];
            asrc[o] = Abase + (size_t)tok * ND + gcolA;
        } else if constexpr (MODE == 1) {
            int gr = min(m0 + r, mcnt - 1);
            asrc[o] = Ab + (size_t)gr * NH + gcolA;
        } else if constexpr (MODE == 2) {
            asrc[o] = Abase + (size_t)(m0 + r) * ND + gcolA;
        } else {
            asrc[o] = Abase + (size_t)(m0 + r) * NHS + gcolA;
        }
        dstA[o] = o * 2048 + wave * 512;        // linear dest (thread -> tid*8)
    }

    // ---- B staging (f32 reg-stage): pass o = 16 rows; lane-col = float4 ----
    const int brow = tid >> 4;                  // 0..15 row within pass
    const int lc = tid & 15;                    // float4 index (k = lc*4)
    const float* bsrc[8];
    int bdst[8];
#pragma unroll
    for (int o = 0; o < 8; o++) {
        int r = o * 16 + brow;                  // tile n-row 0..127
        bsrc[o] = Bb + (size_t)(n0 + r) * K + lc * 4;   // linear global source
        int ks = lc >> 1;                       // logical 16B slot 0..7
        bdst[o] = r * 64 + ((ks ^ (r & 7)) * 8) + (lc & 1) * 4;  // swizzled dest
    }

    // A stage for tile tt -> As[tt&1]
    auto STAGE_A = [&](int tt, int par) {
        const int ko = (tt < NTILES ? tt : NTILES - 1) * 64;
        short* Ad = As[par];
#pragma unroll
        for (int o = 0; o < 4; o++) gload_lds16(asrc[o] + ko, Ad + dstA[o]);
    };
    // B global->regs for tile tt
    auto BLOAD = [&](int tt, f32x4* regs) {
        const int ko = (tt < NTILES ? tt : NTILES - 1) * 64;
#pragma unroll
        for (int o = 0; o < 8; o++) regs[o] = *(const f32x4*)(bsrc[o] + ko);
    };
    // B regs -> cvt -> swizzled LDS write into Bs[par]
    auto BWRITE = [&](const f32x4* regs, int par) {
        short* Bd = Bs[par];
#pragma unroll
        for (int o = 0; o < 8; o++) {
            short4 h;
            h.x = f2bf(regs[o][0]); h.y = f2bf(regs[o][1]);
            h.z = f2bf(regs[o][2]); h.w = f2bf(regs[o][3]);
            *(short4*)(Bd + bdst[o]) = h;
        }
    };

    // ---- fragment read offsets (kh=0; kh=1 = off ^ 32) ----
    const int r16 = lane & 15;
    const int physbase = ((lane >> 4) ^ (lane & 7)) * 8;
    int offA[4], offB[4];
#pragma unroll
    for (int m = 0; m < 4; m++)
        offA[m] = (wr * 64 + m * 16 + r16) * 64 + physbase;
#pragma unroll
    for (int n = 0; n < 4; n++)
        offB[n] = (wc * 64 + n * 16 + r16) * 64 + physbase;

    f32x4 acc[4][4] = {};
    f32x4 br0[8], br1[8], br2[8], br3[8];    // 4-deep B reg pipeline

    // ---- prologue: queue = [A0 4, A1 4, B0 8, B1 8, B2 8, B3 8] = 40 ----
    STAGE_A(0, 0); STAGE_A(1, 1);
    BLOAD(0, br0); BLOAD(1, br1); BLOAD(2, br2); BLOAD(3, br3);
    asm volatile("s_waitcnt vmcnt(24)" ::: "memory");   // retire A0, A1, B0
    __builtin_amdgcn_sched_barrier(0);
    BWRITE(br0, 0);
    asm volatile("s_waitcnt lgkmcnt(0)" ::: "memory");
    __builtin_amdgcn_sched_barrier(0);

    // ---- main loop: 4 tiles/iter (static reg parity) ----
#define GEMM_ITER(T, PAR, CONSUME, FILL)                                        \
    {                                                                           \
        __builtin_amdgcn_s_barrier();                                           \
        __builtin_amdgcn_sched_barrier(0);                                      \
        const short* At = As[PAR];                                              \
        const short* Bt = Bs[PAR];                                              \
        s16x8 af[4], bf[4];                                                     \
        _Pragma("unroll")                                                       \
        for (int m = 0; m < 4; m++) af[m] = *(const s16x8*)(At + offA[m]);      \
        _Pragma("unroll")                                                       \
        for (int n = 0; n < 4; n++) bf[n] = *(const s16x8*)(Bt + offB[n]);      \
        asm volatile("s_waitcnt lgkmcnt(0)" ::: "memory");                      \
        __builtin_amdgcn_sched_barrier(0);                                      \
        __builtin_amdgcn_s_setprio(1);                                          \
        _Pragma("unroll")                                                       \
        for (int m = 0; m < 4; m++)                                             \
            _Pragma("unroll")                                                   \
            for (int n = 0; n < 4; n++)                                         \
                acc[m][n] = __builtin_amdgcn_mfma_f32_16x16x32_bf16(            \
                    af[m], bf[n], acc[m][n], 0, 0, 0);                          \
        __builtin_amdgcn_s_setprio(0);                                          \
        s16x8 ag[4], bg[4];                                                     \
        _Pragma("unroll")                                                       \
        for (int m = 0; m < 4; m++) ag[m] = *(const s16x8*)(At + (offA[m] ^ 32)); \
        _Pragma("unroll")                                                       \
        for (int n = 0; n < 4; n++) bg[n] = *(const s16x8*)(Bt + (offB[n] ^ 32)); \
        asm volatile("s_waitcnt lgkmcnt(0)" ::: "memory");                      \
        __builtin_amdgcn_sched_barrier(0);                                      \
        __builtin_amdgcn_s_barrier();  /* all waves done with buf[PAR] */       \
        __builtin_amdgcn_sched_barrier(0);                                      \
        STAGE_A((T) + 2, PAR);                                                  \
        BLOAD((T) + 4, FILL);                                                   \
        asm volatile("s_waitcnt vmcnt(20)" ::: "memory"); /* B(T+2),A(T+1) in */ \
        __builtin_amdgcn_sched_barrier(0);                                      \
        BWRITE(CONSUME, (PAR) ^ 1);   /* B(T+1) -> Bs[(T+1)&1] */               \
        __builtin_amdgcn_s_setprio(1);                                          \
        _Pragma("unroll")                                                       \
        for (int m = 0; m < 4; m++)                                             \
            _Pragma("unroll")                                                   \
            for (int n = 0; n < 4; n++)                                         \
                acc[m][n] = __builtin_amdgcn_mfma_f32_16x16x32_bf16(            \
                    ag[m], bg[n], acc[m][n], 0, 0, 0);                          \
        __builtin_amdgcn_s_setprio(0);                                          \
        asm volatile("s_waitcnt lgkmcnt(0)" ::: "memory");                      \
        __builtin_amdgcn_sched_barrier(0);                                      \
    }

    for (int t = 0; t < NTILES; t += 4) {
        GEMM_ITER(t + 0, 0, br1, br0);   // write B(t+1), load B(t+4)->br0
        GEMM_ITER(t + 1, 1, br2, br1);   // write B(t+2), load B(t+5)->br1
        GEMM_ITER(t + 2, 0, br3, br2);   // write B(t+3), load B(t+6)->br2
        GEMM_ITER(t + 3, 1, br0, br3);   // write B(t+4), load B(t+7)->br3
    }
#undef GEMM_ITER

    // ---- epilogue ----  C mapping: col = lane&15, row = (lane>>4)*4 + reg
    const int r0 = (lane >> 4) * 4;
    const int cc = lane & 15;

    if constexpr (MODE == 0 || MODE == 2) {
#pragma unroll
        for (int i = 0; i < 4; i++)
#pragma unroll
            for (int j = 0; j < 4; j++)
#pragma unroll
                for (int v = 0; v < 4; v++) {
                    int row = wr * 64 + i * 16 + r0 + v;
                    int col = wc * 64 + j * 16 + cc;
                    float val = acc[i][j][v];
                    float r = fmaxf(val, 0.f);
                    val = r * r;
                    if constexpr (MODE == 0)
                        Hout[((size_t)e * CAPE + m0 + row) * NH + (n0 + col)] = f2bf(val);
                    else
                        Hout[(size_t)(m0 + row) * NHS + (n0 + col)] = f2bf(val);
                }
    } else if constexpr (MODE == 3) {
#pragma unroll
        for (int i = 0; i < 4; i++)
#pragma unroll
            for (int j = 0; j < 4; j++)
#pragma unroll
                for (int v = 0; v < 4; v++) {
                    int row = wr * 64 + i * 16 + r0 + v;
                    int col = wc * 64 + j * 16 + cc;
                    out[(size_t)(m0 + row) * ND + (n0 + col)] = acc[i][j][v];
                }
    } else {  // MODE 1: bf16 store to Ybuf, valid rows only
#pragma unroll
        for (int i = 0; i < 4; i++)
#pragma unroll
            for (int v = 0; v < 4; v++) {
                int row = wr * 64 + i * 16 + r0 + v;
                int grow = m0 + row;
                if (grow < mcnt) {
#pragma unroll
                    for (int j = 0; j < 4; j++) {
                        int col = wc * 64 + j * 16 + cc;
                        Hout[((size_t)e * CAPE + grow) * ND + (n0 + col)] = f2bf(acc[i][j][v]);
                    }
                }
            }
    }
}

// ---------------------------------------------------------------------------
extern "C" void kernel_launch(void* const* d_in, const int* in_sizes, int n_in,
                              void* d_out, int out_size, void* d_ws, size_t ws_size,
                              hipStream_t stream) {
    const float* X    = (const float*)d_in[0];
    const float* Gw   = (const float*)d_in[1];
    const float* bias = (const float*)d_in[2];
    const float* up_w = (const float*)d_in[3];
    const float* dn_w = (const float*)d_in[4];
    const float* sup  = (const float*)d_in[5];
    const float* sdn  = (const float*)d_in[6];
    float* out = (float*)d_out;

    char* ws = (char*)d_ws;
    size_t off = 0;
    auto alloc = [&](size_t bytes) -> void* {
        off = (off + 255) & ~(size_t)255;
        void* p = ws + off;
        off += bytes;
        return p;
    };
    int*   cnt      = (int*)  alloc(NE * 4);
    int*   topk_idx = (int*)  alloc((size_t)NT * NK * 4);
    float* topk_w   = (float*)alloc((size_t)NT * NK * 4);
    int*   pos_list = (int*)  alloc((size_t)NT * NK * 4);
    int*   tok_list = (int*)  alloc((size_t)NE * CAPE * 4);
    short* Hbuf     = (short*)alloc((size_t)NE * CAPE * NH * 2);   // 64 MB
    short* Sbuf     = (short*)alloc((size_t)NT * NHS * 2);         // 32 MB
    short* Xbf      = (short*)alloc((size_t)NT * ND * 2);          // 16 MB
    short* Ybuf     = (short*)alloc((size_t)NE * CAPE * ND * 2);   // 128 MB

    gate_kernel<<<dim3(NT / 4), dim3(256), 0, stream>>>(X, Gw, bias, topk_idx, topk_w);
    zero_cnt<<<dim3(1), dim3(64), 0, stream>>>(cnt);
    dispatch_kernel<<<dim3(NT * NK / 256), dim3(256), 0, stream>>>(
        topk_idx, cnt, tok_list, pos_list);

    // only X needs pre-conversion (weights consumed as f32 in-GEMM)
    cvt_f2bf<<<dim3(1024), dim3(256), 0, stream>>>(X, Xbf, NT * ND / 8);

    // routed up: X gathered -> Hbuf
    moe_gemm4<0><<<dim3(NH / 128, CAPE / 128, NE), dim3(256), 0, stream>>>(
        Xbf, up_w, cnt, tok_list, Hbuf, nullptr);
    // shared up: X -> Sbuf
    moe_gemm4<2><<<dim3(NHS / 128, NT / 128, 1), dim3(256), 0, stream>>>(
        Xbf, sup, nullptr, nullptr, Sbuf, nullptr);
    // shared down: Sbuf -> out (f32 write; MUST precede combine)
    moe_gemm4<3><<<dim3(ND / 128, NT / 128, 1), dim3(256), 0, stream>>>(
        Sbuf, sdn, nullptr, nullptr, nullptr, out);
    // routed down: Hbuf -> Ybuf
    moe_gemm4<1><<<dim3(ND / 128, CAPE / 128, NE), dim3(256), 0, stream>>>(
        Hbuf, dn_w, cnt, tok_list, Ybuf, nullptr);
    // combine: out += sum_k w_k * Ybuf[e_k, pos_k]
    combine_kernel<<<dim3(NT), dim3(256), 0, stream>>>(
        topk_idx, topk_w, pos_list, Ybuf, out);
}

// Round 13
// 636.988 us; speedup vs baseline: 2.3560x; 2.3560x over previous
//
#include <hip/hip_runtime.h>

#define NE 32
#define NG 8
#define NK 4
#define ND 2048
#define NH 1024
#define NHS 4096
#define CAPE 1024
#define NT 4096

typedef float f32x4 __attribute__((ext_vector_type(4)));
typedef short s16x8 __attribute__((ext_vector_type(8)));

__device__ __forceinline__ short f2bf(float f) {
    return __builtin_bit_cast(short, (__bf16)f);
}
__device__ __forceinline__ float bf2f(short h) {
    return __builtin_bit_cast(float, ((unsigned)(unsigned short)h) << 16);
}

__device__ __forceinline__ void gload_lds16(const void* g, void* l) {
    __builtin_amdgcn_global_load_lds(
        (const __attribute__((address_space(1))) void*)g,
        (__attribute__((address_space(3))) void*)l, 16, 0, 0);
}

// ---------------------------------------------------------------------------
// Kernel 1: gating (+ cnt zeroing in block 0). One wave per token.
// ---------------------------------------------------------------------------
__global__ __launch_bounds__(256) void gate_kernel(
    const float* __restrict__ X, const float* __restrict__ Gw,
    const float* __restrict__ bias,
    int* __restrict__ topk_idx, float* __restrict__ topk_w,
    int* __restrict__ cnt)
{
    if (blockIdx.x == 0 && threadIdx.x < NE) cnt[threadIdx.x] = 0;

    const int lane = threadIdx.x & 63;
    const int t = blockIdx.x * 4 + (threadIdx.x >> 6);
    const float* x = X + (size_t)t * ND;

    float xr[32];
#pragma unroll
    for (int i = 0; i < 32; i++) xr[i] = x[lane + i * 64];

    float scores[32];
#pragma unroll
    for (int e = 0; e < 32; e++) {
        const float* w = Gw + (size_t)e * ND;
        float a = 0.f;
#pragma unroll
        for (int i = 0; i < 32; i++) a = fmaf(xr[i], w[lane + i * 64], a);
#pragma unroll
        for (int s = 32; s > 0; s >>= 1) a += __shfl_xor(a, s);
        scores[e] = 1.0f / (1.0f + expf(-a));
    }

    float sc_c[32];
#pragma unroll
    for (int e = 0; e < 32; e++) sc_c[e] = scores[e] + bias[e];

    float gs[8];
#pragma unroll
    for (int g = 0; g < 8; g++) {
        float a = sc_c[4 * g], b = sc_c[4 * g + 1], c = sc_c[4 * g + 2], d = sc_c[4 * g + 3];
        float hi1 = fmaxf(a, b), lo1 = fminf(a, b);
        float hi2 = fmaxf(c, d), lo2 = fminf(c, d);
        float m1 = fmaxf(hi1, hi2);
        float m2 = fmaxf(fminf(hi1, hi2), fmaxf(lo1, lo2));
        gs[g] = m1 + m2;
    }

    unsigned gsel = 0;
#pragma unroll
    for (int it = 0; it < 4; it++) {
        int best = -1; float bv = -1e30f;
#pragma unroll
        for (int g = 0; g < 8; g++) {
            bool avail = !((gsel >> g) & 1);
            if (avail && gs[g] > bv) { bv = gs[g]; best = g; }
        }
        gsel |= 1u << best;
    }

    unsigned esel = 0;
    int idxs[4]; float wts[4];
#pragma unroll
    for (int it = 0; it < 4; it++) {
        int best = -1; float bv = -1e30f, braw = 0.f;
#pragma unroll
        for (int e = 0; e < 32; e++) {
            float mv = ((gsel >> (e >> 2)) & 1) ? sc_c[e] : 0.0f;
            bool avail = !((esel >> e) & 1);
            if (avail && mv > bv) { bv = mv; best = e; braw = scores[e]; }
        }
        esel |= 1u << best;
        idxs[it] = best; wts[it] = braw;
    }

    float s = wts[0] + wts[1] + wts[2] + wts[3] + 1e-20f;
    if (lane == 0) {
#pragma unroll
        for (int k = 0; k < 4; k++) {
            topk_idx[t * 4 + k] = idxs[k];
            topk_w[t * 4 + k] = wts[k] / s * 2.5f;
        }
    }
}

// ---------------------------------------------------------------------------
__global__ void dispatch_kernel(const int* __restrict__ topk_idx,
                                int* __restrict__ cnt,
                                int* __restrict__ tok_list,
                                int* __restrict__ pos_list)
{
    int i = blockIdx.x * 256 + threadIdx.x;
    int e = topk_idx[i];
    int t = i >> 2;
    int pos = atomicAdd(&cnt[e], 1);
    pos_list[i] = pos;
    if (pos < CAPE) {
        tok_list[e * CAPE + pos] = t;
    }
}

// ---------------------------------------------------------------------------
// f32 -> bf16 bulk conversion (X only)
// ---------------------------------------------------------------------------
__global__ __launch_bounds__(256) void cvt_f2bf(const float* __restrict__ in,
                                                short* __restrict__ out, int n8)
{
    int i = blockIdx.x * 256 + threadIdx.x;
    int stride = gridDim.x * 256;
    for (; i < n8; i += stride) {
        const f32x4* p = (const f32x4*)(in + (size_t)i * 8);
        f32x4 a = p[0], b = p[1];
        s16x8 h;
        h[0] = f2bf(a[0]); h[1] = f2bf(a[1]); h[2] = f2bf(a[2]); h[3] = f2bf(a[3]);
        h[4] = f2bf(b[0]); h[5] = f2bf(b[1]); h[6] = f2bf(b[2]); h[7] = f2bf(b[3]);
        *(s16x8*)(out + (size_t)i * 8) = h;
    }
}

// ---------------------------------------------------------------------------
// Combine: out[t] = shared_down[t] (already in out) + sum_k w_k * Ybuf[e_k,pos_k]
// ---------------------------------------------------------------------------
__global__ __launch_bounds__(256) void combine_kernel(
    const int* __restrict__ topk_idx, const float* __restrict__ topk_w,
    const int* __restrict__ pos_list,
    const short* __restrict__ Ybuf, float* __restrict__ out)
{
    const int t = blockIdx.x;
    const int d0 = threadIdx.x * 8;

    int e[NK], p[NK]; float w[NK];
#pragma unroll
    for (int k = 0; k < NK; k++) {
        e[k] = topk_idx[t * NK + k];
        p[k] = pos_list[t * NK + k];
        w[k] = topk_w[t * NK + k];
    }

    float* orow = out + (size_t)t * ND + d0;
    f32x4 o0 = *(f32x4*)(orow);
    f32x4 o1 = *(f32x4*)(orow + 4);

#pragma unroll
    for (int k = 0; k < NK; k++) {
        if (p[k] < CAPE) {
            s16x8 y = *(const s16x8*)(Ybuf + ((size_t)e[k] * CAPE + p[k]) * ND + d0);
            o0[0] = fmaf(w[k], bf2f(y[0]), o0[0]);
            o0[1] = fmaf(w[k], bf2f(y[1]), o0[1]);
            o0[2] = fmaf(w[k], bf2f(y[2]), o0[2]);
            o0[3] = fmaf(w[k], bf2f(y[3]), o0[3]);
            o1[0] = fmaf(w[k], bf2f(y[4]), o1[0]);
            o1[1] = fmaf(w[k], bf2f(y[5]), o1[1]);
            o1[2] = fmaf(w[k], bf2f(y[6]), o1[2]);
            o1[3] = fmaf(w[k], bf2f(y[7]), o1[3]);
        }
    }
    *(f32x4*)(orow) = o0;
    *(f32x4*)(orow + 4) = o1;
}

// ---------------------------------------------------------------------------
// R10-verified GEMM inner loop as a macro set, shared by both fused kernels.
// 128x128, BK=64, As[2]+Bs[2] 64KB LDS -> 2 blk/CU. A via gload_lds (swizzled
// source); B f32 reg-staged (2-deep) -> cvt -> swizzled ds_write. Early-BLOAD:
// B(T+3) issued after bar1 (ledger: vmcnt(12) retires {B(T+2), A(T+1)}).
// ---------------------------------------------------------------------------
#define GEMM_BODY_SETUP()                                                       \
    __shared__ short As[2][128 * 64];                                           \
    __shared__ short Bs[2][128 * 64];                                           \
    const int tid = threadIdx.x;                                                \
    const int lane = tid & 63;                                                  \
    const int wave = tid >> 6;                                                  \
    const int wr = wave >> 1, wc = wave & 1;                                    \
    const int srow = tid >> 3;                                                  \
    const int pA = tid & 7;                                                     \
    const int gcolA = (pA ^ (srow & 7)) * 8;                                    \
    const int brow = tid >> 4;                                                  \
    const int lc = tid & 15;                                                    \
    const int r16 = lane & 15;                                                  \
    const int physbase = ((lane >> 4) ^ (lane & 7)) * 8;                        \
    int offA[4], offB[4];                                                       \
    _Pragma("unroll")                                                           \
    for (int m = 0; m < 4; m++) offA[m] = (wr * 64 + m * 16 + r16) * 64 + physbase; \
    _Pragma("unroll")                                                           \
    for (int n = 0; n < 4; n++) offB[n] = (wc * 64 + n * 16 + r16) * 64 + physbase;

#define GEMM_ITER(T, PAR, CONSUME, FILL)                                        \
    {                                                                           \
        __builtin_amdgcn_s_barrier();                                           \
        __builtin_amdgcn_sched_barrier(0);                                      \
        BLOAD((T) + 3, FILL);                                                   \
        const short* At = As[PAR];                                              \
        const short* Bt = Bs[PAR];                                              \
        s16x8 af[4], bf[4];                                                     \
        _Pragma("unroll")                                                       \
        for (int m = 0; m < 4; m++) af[m] = *(const s16x8*)(At + offA[m]);      \
        _Pragma("unroll")                                                       \
        for (int n = 0; n < 4; n++) bf[n] = *(const s16x8*)(Bt + offB[n]);      \
        asm volatile("s_waitcnt lgkmcnt(0)" ::: "memory");                      \
        __builtin_amdgcn_sched_barrier(0);                                      \
        __builtin_amdgcn_s_setprio(1);                                          \
        _Pragma("unroll")                                                       \
        for (int m = 0; m < 4; m++)                                             \
            _Pragma("unroll")                                                   \
            for (int n = 0; n < 4; n++)                                         \
                acc[m][n] = __builtin_amdgcn_mfma_f32_16x16x32_bf16(            \
                    af[m], bf[n], acc[m][n], 0, 0, 0);                          \
        __builtin_amdgcn_s_setprio(0);                                          \
        s16x8 ag[4], bg[4];                                                     \
        _Pragma("unroll")                                                       \
        for (int m = 0; m < 4; m++) ag[m] = *(const s16x8*)(At + (offA[m] ^ 32)); \
        _Pragma("unroll")                                                       \
        for (int n = 0; n < 4; n++) bg[n] = *(const s16x8*)(Bt + (offB[n] ^ 32)); \
        asm volatile("s_waitcnt lgkmcnt(0)" ::: "memory");                      \
        __builtin_amdgcn_sched_barrier(0);                                      \
        __builtin_amdgcn_s_barrier();  /* all waves done with buf[PAR] */       \
        __builtin_amdgcn_sched_barrier(0);                                      \
        STAGE_A((T) + 2, PAR);                                                  \
        asm volatile("s_waitcnt vmcnt(12)" ::: "memory"); /* B(T+2),A(T+1) in */ \
        __builtin_amdgcn_sched_barrier(0);                                      \
        BWRITE(CONSUME, PAR);         /* B(T+2) -> Bs[PAR] */                   \
        __builtin_amdgcn_s_setprio(1);                                          \
        _Pragma("unroll")                                                       \
        for (int m = 0; m < 4; m++)                                             \
            _Pragma("unroll")                                                   \
            for (int n = 0; n < 4; n++)                                         \
                acc[m][n] = __builtin_amdgcn_mfma_f32_16x16x32_bf16(            \
                    ag[m], bg[n], acc[m][n], 0, 0, 0);                          \
        __builtin_amdgcn_s_setprio(0);                                          \
        asm volatile("s_waitcnt lgkmcnt(0)" ::: "memory");                      \
        __builtin_amdgcn_sched_barrier(0);                                      \
    }

#define GEMM_PROLOGUE()                                                         \
    STAGE_A(0, 0); STAGE_A(1, 1);                                               \
    BLOAD(0, brE); BLOAD(1, brO);                                               \
    asm volatile("s_waitcnt vmcnt(8)" ::: "memory");                            \
    __builtin_amdgcn_sched_barrier(0);                                          \
    BWRITE(brE, 0);                                                             \
    asm volatile("s_waitcnt vmcnt(0)" ::: "memory");                            \
    __builtin_amdgcn_sched_barrier(0);                                          \
    BWRITE(brO, 1);                                                             \
    BLOAD(2, brE);                                                              \
    asm volatile("s_waitcnt lgkmcnt(0)" ::: "memory");                          \
    __builtin_amdgcn_sched_barrier(0);

// ---------------------------------------------------------------------------
// Fused UP kernel: routed-up (bid < 2048) + shared-up (bid >= 2048). K = ND.
// ---------------------------------------------------------------------------
__global__ __launch_bounds__(256, 2) void fused_up(
    const short* __restrict__ Xbf, const float* __restrict__ up_w,
    const float* __restrict__ sup,
    const int* __restrict__ cnt, const int* __restrict__ tok_list,
    short* __restrict__ Hbuf, short* __restrict__ Sbuf)
{
    constexpr int K = ND;
    constexpr int NTILES = K / 64;

    const int bid = blockIdx.x;
    const bool routed = bid < 2048;
    int e = 0, m0, n0, mcnt = 0;
    const float* Bb;
    if (routed) {
        e = bid >> 6;
        m0 = ((bid >> 3) & 7) * 128;
        n0 = (bid & 7) * 128;
        mcnt = min(cnt[e], CAPE);
        if (m0 >= mcnt) return;
        Bb = up_w + (size_t)e * NH * ND;
    } else {
        int lin = bid - 2048;
        m0 = (lin >> 5) * 128;
        n0 = (lin & 31) * 128;
        Bb = sup;
    }

    GEMM_BODY_SETUP();

    const short* asrc[4];
    int dstA[4];
#pragma unroll
    for (int o = 0; o < 4; o++) {
        int r = o * 32 + srow;
        int arow;
        if (routed) {
            int gr = min(m0 + r, mcnt - 1);
            arow = tok_list[e * CAPE + gr];
        } else {
            arow = m0 + r;
        }
        asrc[o] = Xbf + (size_t)arow * ND + gcolA;
        dstA[o] = o * 2048 + wave * 512;
    }

    const float* bsrc[8];
    int bdst[8];
#pragma unroll
    for (int o = 0; o < 8; o++) {
        int r = o * 16 + brow;
        bsrc[o] = Bb + (size_t)(n0 + r) * K + lc * 4;
        int ks = lc >> 1;
        bdst[o] = r * 64 + ((ks ^ (r & 7)) * 8) + (lc & 1) * 4;
    }

    auto STAGE_A = [&](int tt, int par) {
        const int ko = (tt < NTILES ? tt : NTILES - 1) * 64;
        short* Ad = As[par];
#pragma unroll
        for (int o = 0; o < 4; o++) gload_lds16(asrc[o] + ko, Ad + dstA[o]);
    };
    auto BLOAD = [&](int tt, f32x4* regs) {
        const int ko = (tt < NTILES ? tt : NTILES - 1) * 64;
#pragma unroll
        for (int o = 0; o < 8; o++) regs[o] = *(const f32x4*)(bsrc[o] + ko);
    };
    auto BWRITE = [&](const f32x4* regs, int par) {
        short* Bd = Bs[par];
#pragma unroll
        for (int o = 0; o < 8; o++) {
            short4 h;
            h.x = f2bf(regs[o][0]); h.y = f2bf(regs[o][1]);
            h.z = f2bf(regs[o][2]); h.w = f2bf(regs[o][3]);
            *(short4*)(Bd + bdst[o]) = h;
        }
    };

    f32x4 acc[4][4] = {};
    f32x4 brE[8], brO[8];

    GEMM_PROLOGUE();
    for (int t = 0; t < NTILES; t += 2) {
        GEMM_ITER(t,     0, brE, brO);
        GEMM_ITER(t + 1, 1, brO, brE);
    }

    // epilogue: relu^2 -> bf16
    const int r0 = (lane >> 4) * 4;
    const int cc = lane & 15;
#pragma unroll
    for (int i = 0; i < 4; i++)
#pragma unroll
        for (int j = 0; j < 4; j++)
#pragma unroll
            for (int v = 0; v < 4; v++) {
                int row = wr * 64 + i * 16 + r0 + v;
                int col = wc * 64 + j * 16 + cc;
                float val = acc[i][j][v];
                float r = fmaxf(val, 0.f);
                val = r * r;
                if (routed)
                    Hbuf[((size_t)e * CAPE + m0 + row) * NH + (n0 + col)] = f2bf(val);
                else
                    Sbuf[(size_t)(m0 + row) * NHS + (n0 + col)] = f2bf(val);
            }
}

// ---------------------------------------------------------------------------
// Fused DOWN kernel: routed-down (bid < 4096, K=NH) + shared-down (K=NHS).
// ---------------------------------------------------------------------------
__global__ __launch_bounds__(256, 2) void fused_dn(
    const short* __restrict__ Hbuf, const short* __restrict__ Sbuf,
    const float* __restrict__ dn_w, const float* __restrict__ sdn,
    const int* __restrict__ cnt, const int* __restrict__ tok_list,
    short* __restrict__ Ybuf, float* __restrict__ out)
{
    const int bid = blockIdx.x;
    const bool routed = bid < 4096;
    int e = 0, m0, n0, mcnt = 0;
    int K;
    const short* Abase;
    const float* Bb;
    if (routed) {
        e = bid >> 7;
        m0 = ((bid >> 4) & 7) * 128;
        n0 = (bid & 15) * 128;
        mcnt = min(cnt[e], CAPE);
        if (m0 >= mcnt) return;
        K = NH;
        Abase = Hbuf + (size_t)e * CAPE * NH;
        Bb = dn_w + (size_t)e * ND * NH;
    } else {
        int lin = bid - 4096;
        m0 = (lin >> 4) * 128;
        n0 = (lin & 15) * 128;
        K = NHS;
        Abase = Sbuf;
        Bb = sdn;
    }
    const int NTILES = K / 64;

    GEMM_BODY_SETUP();

    const short* asrc[4];
    int dstA[4];
#pragma unroll
    for (int o = 0; o < 4; o++) {
        int r = o * 32 + srow;
        int arow = routed ? min(m0 + r, mcnt - 1) : (m0 + r);
        asrc[o] = Abase + (size_t)arow * K + gcolA;
        dstA[o] = o * 2048 + wave * 512;
    }

    const float* bsrc[8];
    int bdst[8];
#pragma unroll
    for (int o = 0; o < 8; o++) {
        int r = o * 16 + brow;
        bsrc[o] = Bb + (size_t)(n0 + r) * K + lc * 4;
        int ks = lc >> 1;
        bdst[o] = r * 64 + ((ks ^ (r & 7)) * 8) + (lc & 1) * 4;
    }

    auto STAGE_A = [&](int tt, int par) {
        const int ko = (tt < NTILES ? tt : NTILES - 1) * 64;
        short* Ad = As[par];
#pragma unroll
        for (int o = 0; o < 4; o++) gload_lds16(asrc[o] + ko, Ad + dstA[o]);
    };
    auto BLOAD = [&](int tt, f32x4* regs) {
        const int ko = (tt < NTILES ? tt : NTILES - 1) * 64;
#pragma unroll
        for (int o = 0; o < 8; o++) regs[o] = *(const f32x4*)(bsrc[o] + ko);
    };
    auto BWRITE = [&](const f32x4* regs, int par) {
        short* Bd = Bs[par];
#pragma unroll
        for (int o = 0; o < 8; o++) {
            short4 h;
            h.x = f2bf(regs[o][0]); h.y = f2bf(regs[o][1]);
            h.z = f2bf(regs[o][2]); h.w = f2bf(regs[o][3]);
            *(short4*)(Bd + bdst[o]) = h;
        }
    };

    f32x4 acc[4][4] = {};
    f32x4 brE[8], brO[8];

    GEMM_PROLOGUE();
    for (int t = 0; t < NTILES; t += 2) {
        GEMM_ITER(t,     0, brE, brO);
        GEMM_ITER(t + 1, 1, brO, brE);
    }

    // epilogue
    const int r0 = (lane >> 4) * 4;
    const int cc = lane & 15;
    if (routed) {
#pragma unroll
        for (int i = 0; i < 4; i++)
#pragma unroll
            for (int v = 0; v < 4; v++) {
                int row = wr * 64 + i * 16 + r0 + v;
                int grow = m0 + row;
                if (grow < mcnt) {
#pragma unroll
                    for (int j = 0; j < 4; j++) {
                        int col = wc * 64 + j * 16 + cc;
                        Ybuf[((size_t)e * CAPE + grow) * ND + (n0 + col)] = f2bf(acc[i][j][v]);
                    }
                }
            }
    } else {
#pragma unroll
        for (int i = 0; i < 4; i++)
#pragma unroll
            for (int j = 0; j < 4; j++)
#pragma unroll
                for (int v = 0; v < 4; v++) {
                    int row = wr * 64 + i * 16 + r0 + v;
                    int col = wc * 64 + j * 16 + cc;
                    out[(size_t)(m0 + row) * ND + (n0 + col)] = acc[i][j][v];
                }
    }
}

// ---------------------------------------------------------------------------
extern "C" void kernel_launch(void* const* d_in, const int* in_sizes, int n_in,
                              void* d_out, int out_size, void* d_ws, size_t ws_size,
                              hipStream_t stream) {
    const float* X    = (const float*)d_in[0];
    const float* Gw   = (const float*)d_in[1];
    const float* bias = (const float*)d_in[2];
    const float* up_w = (const float*)d_in[3];
    const float* dn_w = (const float*)d_in[4];
    const float* sup  = (const float*)d_in[5];
    const float* sdn  = (const float*)d_in[6];
    float* out = (float*)d_out;

    char* ws = (char*)d_ws;
    size_t off = 0;
    auto alloc = [&](size_t bytes) -> void* {
        off = (off + 255) & ~(size_t)255;
        void* p = ws + off;
        off += bytes;
        return p;
    };
    int*   cnt      = (int*)  alloc(NE * 4);
    int*   topk_idx = (int*)  alloc((size_t)NT * NK * 4);
    float* topk_w   = (float*)alloc((size_t)NT * NK * 4);
    int*   pos_list = (int*)  alloc((size_t)NT * NK * 4);
    int*   tok_list = (int*)  alloc((size_t)NE * CAPE * 4);
    short* Hbuf     = (short*)alloc((size_t)NE * CAPE * NH * 2);   // 64 MB
    short* Sbuf     = (short*)alloc((size_t)NT * NHS * 2);         // 32 MB
    short* Xbf      = (short*)alloc((size_t)NT * ND * 2);          // 16 MB
    short* Ybuf     = (short*)alloc((size_t)NE * CAPE * ND * 2);   // 128 MB

    gate_kernel<<<dim3(NT / 4), dim3(256), 0, stream>>>(X, Gw, bias, topk_idx, topk_w, cnt);
    dispatch_kernel<<<dim3(NT * NK / 256), dim3(256), 0, stream>>>(
        topk_idx, cnt, tok_list, pos_list);

    cvt_f2bf<<<dim3(1024), dim3(256), 0, stream>>>(X, Xbf, NT * ND / 8);

    // fused up: routed (2048 blocks) + shared (1024 blocks)
    fused_up<<<dim3(2048 + 1024), dim3(256), 0, stream>>>(
        Xbf, up_w, sup, cnt, tok_list, Hbuf, Sbuf);
    // fused down: routed (4096 blocks) + shared (512 blocks)
    fused_dn<<<dim3(4096 + 512), dim3(256), 0, stream>>>(
        Hbuf, Sbuf, dn_w, sdn, cnt, tok_list, Ybuf, out);
    // combine: out += sum_k w_k * Ybuf[e_k, pos_k]
    combine_kernel<<<dim3(NT), dim3(256), 0, stream>>>(
        topk_idx, topk_w, pos_list, Ybuf, out);
}